// Round 5
// baseline (101.646 us; speedup 1.0000x reference)
//
#include <hip/hip_runtime.h>
#include <math.h>

#define Lc 2048
#define Bc 64
#define Hc 1024
#define NWAVE 8192          // persistent waves; each handles 16 rows, stride 8192
#define ITERS 16            // (Lc*Bc) / NWAVE

// ---------------- kernel 1: pure streaming dot ------------------------------------
// Wave w handles rows r = w + it*8192, it = 0..15. Note (r & 63) == (w & 63),
// so b is FIXED per wave -> hidden[b] loads once into registers.
// Ping-pong prefetch keeps next row's enc loads in flight during the reduce.
__global__ __launch_bounds__(256) void energy_kernel(const float* __restrict__ hidden,
                                                     const float* __restrict__ enc,
                                                     float* __restrict__ energies) {
    int wid  = threadIdx.x >> 6;
    int lane = threadIdx.x & 63;
    int w    = blockIdx.x * 4 + wid;    // wave id in [0, NWAVE)
    int b    = w & (Bc - 1);            // fixed b for this wave
    int l0   = w >> 6;                  // l = l0 + it*128

    const float4* __restrict__ hrow = (const float4*)(hidden + (size_t)b * Hc);
    float4 h0 = hrow[0 * 64 + lane];
    float4 h1 = hrow[1 * 64 + lane];
    float4 h2 = hrow[2 * 64 + lane];
    float4 h3 = hrow[3 * 64 + lane];

    const float4* __restrict__ base = (const float4*)enc;   // row r at r*256
    size_t off = (size_t)w * 256 + lane;                    // float4 index
    const size_t RSTRIDE = (size_t)NWAVE * 256;             // next row for this wave

    float4 a0 = base[off], a1 = base[off + 64], a2 = base[off + 128], a3 = base[off + 192];
    float4 c0 = a0, c1 = a1, c2 = a2, c3 = a3;

    for (int it = 0; it < ITERS; ++it) {
        size_t noff = off + RSTRIDE;
        if (it < ITERS - 1) {           // prefetch next row
            c0 = base[noff];
            c1 = base[noff + 64];
            c2 = base[noff + 128];
            c3 = base[noff + 192];
        }
        float acc = a0.x * h0.x + a0.y * h0.y + a0.z * h0.z + a0.w * h0.w
                  + a1.x * h1.x + a1.y * h1.y + a1.z * h1.z + a1.w * h1.w
                  + a2.x * h2.x + a2.y * h2.y + a2.z * h2.z + a2.w * h2.w
                  + a3.x * h3.x + a3.y * h3.y + a3.z * h3.z + a3.w * h3.w;
        for (int o = 1; o < 64; o <<= 1) acc += __shfl_xor(acc, o);
        if (lane == 0) energies[(size_t)b * Lc + l0 + it * 128] = acc;
        a0 = c0; a1 = c1; a2 = c2; a3 = c3;
        off = noff;
    }
}

// ---------------- kernel 2: ha + affect + row softmax ------------------------------
__global__ __launch_bounds__(256) void softmax_kernel(const float* __restrict__ hidden,
                                                      const float* __restrict__ emb,
                                                      const float* __restrict__ am,
                                                      const float* __restrict__ energies,
                                                      float* __restrict__ out) {
    int b = blockIdx.x;
    int t = threadIdx.x;
    int wave = t >> 6;

    // ---- phase 1: ha (block reduce) ----
    float s0 = 0.f, s1 = 0.f, s2 = 0.f;
#pragma unroll
    for (int i = 0; i < 4; ++i) {        // 4 * 256 = 1024 = H
        int h = t + i * 256;
        float hv = hidden[b * Hc + h];
        s0 += hv * am[h * 3 + 0];
        s1 += hv * am[h * 3 + 1];
        s2 += hv * am[h * 3 + 2];
    }
    for (int off = 1; off < 64; off <<= 1) {
        s0 += __shfl_xor(s0, off);
        s1 += __shfl_xor(s1, off);
        s2 += __shfl_xor(s2, off);
    }
    __shared__ float red[3][4];
    if ((t & 63) == 0) { red[0][wave] = s0; red[1][wave] = s1; red[2][wave] = s2; }
    __syncthreads();
    float ha0 = red[0][0] + red[0][1] + red[0][2] + red[0][3];
    float ha1 = red[1][0] + red[1][1] + red[1][2] + red[1][3];
    float ha2 = red[2][0] + red[2][1] + red[2][2] + red[2][3];
    __syncthreads();

    // ---- phase 2: affect + softmax ----
    const float* row = energies + (size_t)b * Lc;
    float vals[8];
    float m = -INFINITY;
#pragma unroll
    for (int i = 0; i < 8; ++i) {        // 8 * 256 = 2048 = L
        int ll = t + i * 256;
        const float* em = emb + ((size_t)ll * Bc + b) * 3;
        float e = row[ll] + ha0 * em[0] + ha1 * em[1] + ha2 * em[2];
        vals[i] = e;
        m = fmaxf(m, e);
    }
    __shared__ float sred[4];
    for (int off = 1; off < 64; off <<= 1) m = fmaxf(m, __shfl_xor(m, off));
    if ((t & 63) == 0) sred[wave] = m;
    __syncthreads();
    m = fmaxf(fmaxf(sred[0], sred[1]), fmaxf(sred[2], sred[3]));
    __syncthreads();

    float s = 0.f;
#pragma unroll
    for (int i = 0; i < 8; ++i) {
        vals[i] = __expf(vals[i] - m);
        s += vals[i];
    }
    for (int off = 1; off < 64; off <<= 1) s += __shfl_xor(s, off);
    if ((t & 63) == 0) sred[wave] = s;
    __syncthreads();
    s = sred[0] + sred[1] + sred[2] + sred[3];
    float inv = 1.0f / s;

#pragma unroll
    for (int i = 0; i < 8; ++i) out[(size_t)b * Lc + t + i * 256] = vals[i] * inv;
}

extern "C" void kernel_launch(void* const* d_in, const int* in_sizes, int n_in,
                              void* d_out, int out_size, void* d_ws, size_t ws_size,
                              hipStream_t stream) {
    const float* hidden = (const float*)d_in[0];   // [1,B,H]
    const float* enc    = (const float*)d_in[1];   // [L,B,H]
    const float* emb    = (const float*)d_in[2];   // [L,B,A]
    const float* am     = (const float*)d_in[3];   // [H,A]
    float* out = (float*)d_out;                    // [B,1,L]

    float* energies = (float*)d_ws;                // B*L floats

    energy_kernel<<<NWAVE / 4, 256, 0, stream>>>(hidden, enc, energies);
    softmax_kernel<<<Bc, 256, 0, stream>>>(hidden, emb, am, energies, out);
}

// Round 6
// 97.177 us; speedup vs baseline: 1.0460x; 1.0460x over previous
//
#include <hip/hip_runtime.h>
#include <math.h>

#define Lc 2048
#define Bc 64
#define Hc 1024

// ---------------- kernel 1: pure streaming dot, 2 rows/wave ------------------------
// Wave w (of 65536): chunk = w>>6, k = w&63. Handles rows r0 = chunk*128 + k and
// r1 = r0 + 64. Both rows share b = k, so hidden[b] is loaded once per wave.
// energies[b, 2*chunk] and [b, 2*chunk+1] written as one float2.
__global__ __launch_bounds__(256) void energy_kernel(const float* __restrict__ hidden,
                                                     const float* __restrict__ enc,
                                                     float* __restrict__ energies) {
    int wid  = threadIdx.x >> 6;
    int lane = threadIdx.x & 63;
    int w    = blockIdx.x * 4 + wid;    // wave id in [0, 65536)
    int k    = w & 63;                  // = b
    int chunk = w >> 6;                 // 128-row chunk

    size_t r0 = (size_t)chunk * 128 + k;

    const float4* __restrict__ e0 = (const float4*)(enc + r0 * Hc);
    const float4* __restrict__ e1 = (const float4*)(enc + (r0 + 64) * Hc);
    const float4* __restrict__ hrow = (const float4*)(hidden + (size_t)k * Hc);

    float acc0 = 0.f, acc1 = 0.f;
#pragma unroll
    for (int i = 0; i < 4; ++i) {        // 4 * 64 lanes * 4 floats = 1024 = H
        float4 h = hrow[i * 64 + lane];
        float4 a = e0[i * 64 + lane];
        float4 c = e1[i * 64 + lane];
        acc0 += a.x * h.x + a.y * h.y + a.z * h.z + a.w * h.w;
        acc1 += c.x * h.x + c.y * h.y + c.z * h.z + c.w * h.w;
    }
    // two independent butterfly chains (compiler can pipeline them)
    for (int off = 1; off < 64; off <<= 1) {
        acc0 += __shfl_xor(acc0, off);
        acc1 += __shfl_xor(acc1, off);
    }

    if (lane == 0) {
        float2 v = make_float2(acc0, acc1);
        *(float2*)(energies + (size_t)k * Lc + 2 * chunk) = v;
    }
}

// ---------------- kernel 2: ha + affect + row softmax ------------------------------
__global__ __launch_bounds__(256) void softmax_kernel(const float* __restrict__ hidden,
                                                      const float* __restrict__ emb,
                                                      const float* __restrict__ am,
                                                      const float* __restrict__ energies,
                                                      float* __restrict__ out) {
    int b = blockIdx.x;
    int t = threadIdx.x;
    int wave = t >> 6;

    // ---- phase 1: ha (block reduce) ----
    float s0 = 0.f, s1 = 0.f, s2 = 0.f;
#pragma unroll
    for (int i = 0; i < 4; ++i) {        // 4 * 256 = 1024 = H
        int h = t + i * 256;
        float hv = hidden[b * Hc + h];
        s0 += hv * am[h * 3 + 0];
        s1 += hv * am[h * 3 + 1];
        s2 += hv * am[h * 3 + 2];
    }
    for (int off = 1; off < 64; off <<= 1) {
        s0 += __shfl_xor(s0, off);
        s1 += __shfl_xor(s1, off);
        s2 += __shfl_xor(s2, off);
    }
    __shared__ float red[3][4];
    if ((t & 63) == 0) { red[0][wave] = s0; red[1][wave] = s1; red[2][wave] = s2; }
    __syncthreads();
    float ha0 = red[0][0] + red[0][1] + red[0][2] + red[0][3];
    float ha1 = red[1][0] + red[1][1] + red[1][2] + red[1][3];
    float ha2 = red[2][0] + red[2][1] + red[2][2] + red[2][3];
    __syncthreads();

    // ---- phase 2: affect + softmax ----
    const float* row = energies + (size_t)b * Lc;
    float vals[8];
    float m = -INFINITY;
#pragma unroll
    for (int i = 0; i < 8; ++i) {        // 8 * 256 = 2048 = L
        int ll = t + i * 256;
        const float* em = emb + ((size_t)ll * Bc + b) * 3;
        float e = row[ll] + ha0 * em[0] + ha1 * em[1] + ha2 * em[2];
        vals[i] = e;
        m = fmaxf(m, e);
    }
    __shared__ float sred[4];
    for (int off = 1; off < 64; off <<= 1) m = fmaxf(m, __shfl_xor(m, off));
    if ((t & 63) == 0) sred[wave] = m;
    __syncthreads();
    m = fmaxf(fmaxf(sred[0], sred[1]), fmaxf(sred[2], sred[3]));
    __syncthreads();

    float s = 0.f;
#pragma unroll
    for (int i = 0; i < 8; ++i) {
        vals[i] = __expf(vals[i] - m);
        s += vals[i];
    }
    for (int off = 1; off < 64; off <<= 1) s += __shfl_xor(s, off);
    if ((t & 63) == 0) sred[wave] = s;
    __syncthreads();
    s = sred[0] + sred[1] + sred[2] + sred[3];
    float inv = 1.0f / s;

#pragma unroll
    for (int i = 0; i < 8; ++i) out[(size_t)b * Lc + t + i * 256] = vals[i] * inv;
}

extern "C" void kernel_launch(void* const* d_in, const int* in_sizes, int n_in,
                              void* d_out, int out_size, void* d_ws, size_t ws_size,
                              hipStream_t stream) {
    const float* hidden = (const float*)d_in[0];   // [1,B,H]
    const float* enc    = (const float*)d_in[1];   // [L,B,H]
    const float* emb    = (const float*)d_in[2];   // [L,B,A]
    const float* am     = (const float*)d_in[3];   // [H,A]
    float* out = (float*)d_out;                    // [B,1,L]

    float* energies = (float*)d_ws;                // B*L floats

    energy_kernel<<<(Lc * Bc / 2) / 4, 256, 0, stream>>>(hidden, enc, energies);
    softmax_kernel<<<Bc, 256, 0, stream>>>(hidden, emb, am, energies, out);
}

// Round 7
// 94.715 us; speedup vs baseline: 1.0732x; 1.0260x over previous
//
#include <hip/hip_runtime.h>
#include <math.h>

#define Lc 2048
#define Bc 64
#define Hc 1024

// ---------------- kernel 1: pure streaming dot (R3-proven, unchanged) -------------
// One wave per row r = l*B + b (enc row is contiguous H floats).
// energies[b,l] = hidden[b,:] . enc[l,b,:]
__global__ __launch_bounds__(256) void energy_kernel(const float* __restrict__ hidden,
                                                     const float* __restrict__ enc,
                                                     float* __restrict__ energies) {
    int wid  = threadIdx.x >> 6;
    int lane = threadIdx.x & 63;
    int r = blockIdx.x * 4 + wid;       // r in [0, L*B)
    int b = r & (Bc - 1);               // B = 64
    int l = r >> 6;                     // r / B

    const float4* __restrict__ erow = (const float4*)(enc + (size_t)r * Hc);
    const float4* __restrict__ hrow = (const float4*)(hidden + (size_t)b * Hc);

    float acc = 0.f;
#pragma unroll
    for (int i = 0; i < 4; ++i) {        // 4 * 64 lanes * 4 floats = 1024 = H
        float4 e = erow[i * 64 + lane];
        float4 h = hrow[i * 64 + lane];
        acc += e.x * h.x + e.y * h.y + e.z * h.z + e.w * h.w;
    }
    for (int off = 1; off < 64; off <<= 1) acc += __shfl_xor(acc, off);

    if (lane == 0) energies[(size_t)b * Lc + l] = acc;
}

// ---------------- kernel 2: ha + affect + row softmax, 1024 threads ----------------
// One block per b, 16 waves. Each thread owns 1 element of H and 2 of L.
__global__ __launch_bounds__(1024) void softmax_kernel(const float* __restrict__ hidden,
                                                       const float* __restrict__ emb,
                                                       const float* __restrict__ am,
                                                       const float* __restrict__ energies,
                                                       float* __restrict__ out) {
    int b = blockIdx.x;
    int t = threadIdx.x;        // 0..1023
    int wave = t >> 6;          // 0..15

    // ---- phase 1: ha[k] = sum_h hidden[b,h]*am[h,k] (one h per thread) ----
    float hv = hidden[b * Hc + t];
    float s0 = hv * am[t * 3 + 0];
    float s1 = hv * am[t * 3 + 1];
    float s2 = hv * am[t * 3 + 2];
    for (int off = 1; off < 64; off <<= 1) {
        s0 += __shfl_xor(s0, off);
        s1 += __shfl_xor(s1, off);
        s2 += __shfl_xor(s2, off);
    }
    __shared__ float red[3][16];
    if ((t & 63) == 0) { red[0][wave] = s0; red[1][wave] = s1; red[2][wave] = s2; }
    __syncthreads();
    float ha0 = 0.f, ha1 = 0.f, ha2 = 0.f;
#pragma unroll
    for (int i = 0; i < 16; ++i) { ha0 += red[0][i]; ha1 += red[1][i]; ha2 += red[2][i]; }

    // ---- phase 2: affect + softmax (two L-elements per thread) ----
    const float* row = energies + (size_t)b * Lc;
    float vals[2];
    float m = -INFINITY;
#pragma unroll
    for (int i = 0; i < 2; ++i) {        // 2 * 1024 = 2048 = L
        int ll = t + i * 1024;
        const float* em = emb + ((size_t)ll * Bc + b) * 3;
        float e = row[ll] + ha0 * em[0] + ha1 * em[1] + ha2 * em[2];
        vals[i] = e;
        m = fmaxf(m, e);
    }
    __shared__ float sredm[16];
    __shared__ float sreds[16];
    for (int off = 1; off < 64; off <<= 1) m = fmaxf(m, __shfl_xor(m, off));
    if ((t & 63) == 0) sredm[wave] = m;
    __syncthreads();
#pragma unroll
    for (int i = 0; i < 16; ++i) m = fmaxf(m, sredm[i]);

    float s = 0.f;
#pragma unroll
    for (int i = 0; i < 2; ++i) {
        vals[i] = __expf(vals[i] - m);
        s += vals[i];
    }
    for (int off = 1; off < 64; off <<= 1) s += __shfl_xor(s, off);
    if ((t & 63) == 0) sreds[wave] = s;
    __syncthreads();
    s = 0.f;
#pragma unroll
    for (int i = 0; i < 16; ++i) s += sreds[i];
    float inv = 1.0f / s;

#pragma unroll
    for (int i = 0; i < 2; ++i) out[(size_t)b * Lc + t + i * 1024] = vals[i] * inv;
}

extern "C" void kernel_launch(void* const* d_in, const int* in_sizes, int n_in,
                              void* d_out, int out_size, void* d_ws, size_t ws_size,
                              hipStream_t stream) {
    const float* hidden = (const float*)d_in[0];   // [1,B,H]
    const float* enc    = (const float*)d_in[1];   // [L,B,H]
    const float* emb    = (const float*)d_in[2];   // [L,B,A]
    const float* am     = (const float*)d_in[3];   // [H,A]
    float* out = (float*)d_out;                    // [B,1,L]

    float* energies = (float*)d_ws;                // B*L floats

    energy_kernel<<<(Lc * Bc) / 4, 256, 0, stream>>>(hidden, enc, energies);
    softmax_kernel<<<Bc, 1024, 0, stream>>>(hidden, emb, am, energies, out);
}